// Round 12
// baseline (284.820 us; speedup 1.0000x reference)
//
#include <hip/hip_runtime.h>

#define INF_F 1e20f
#define B_ 16
#define Q_ 64
#define M_ 512
#define F_ 16
#define D_ 512

typedef __attribute__((ext_vector_type(8))) short short8v;
typedef __attribute__((ext_vector_type(4))) float f32x4;

static __device__ __forceinline__ float bits_f(unsigned u) { return __uint_as_float(u); }

// float4 -> hi bf16x4 (uint2) + residual-lo bf16x4 (uint2), truncation split
static __device__ __forceinline__ void split4(float4 v, uint2& H, uint2& L) {
    unsigned hx = __float_as_uint(v.x) & 0xffff0000u, hy = __float_as_uint(v.y) & 0xffff0000u;
    unsigned hz = __float_as_uint(v.z) & 0xffff0000u, hw = __float_as_uint(v.w) & 0xffff0000u;
    H.x = (hx >> 16) | hy;
    H.y = (hz >> 16) | hw;
    L.x = (__float_as_uint(v.x - bits_f(hx)) >> 16) | (__float_as_uint(v.y - bits_f(hy)) & 0xffff0000u);
    L.y = (__float_as_uint(v.z - bits_f(hz)) >> 16) | (__float_as_uint(v.w - bits_f(hw)) & 0xffff0000u);
}

static __device__ __forceinline__ short8v mk8(uint2 a, uint2 b) {
    union { uint4 u; short8v s; } r;
    r.u = make_uint4(a.x, a.y, b.x, b.y);
    return r.s;
}

// K0: q fragment-image: unit u = [b][kc][lg][row] -> 8 bf16 (hi & lo)
// containing query[b][row][kc*32 + lg*8 .. +7]
__global__ __launch_bounds__(256) void k_q_split(
    const float* __restrict__ q, short8v* __restrict__ qh, short8v* __restrict__ ql)
{
    int u = blockIdx.x * 256 + threadIdx.x;          // 0..65535
    int row = u & 63, lg = (u >> 6) & 3, kc = (u >> 8) & 15, b = u >> 12;
    const float4* q4 = (const float4*)q;
    size_t s = (size_t)(b * 64 + row) * 128 + kc * 8 + lg * 2;
    float4 v0 = q4[s], v1 = q4[s + 1];
    uint2 H0, L0, H1, L1;
    split4(v0, H0, L0);
    split4(v1, H1, L1);
    *(uint4*)&qh[u] = make_uint4(H0.x, H0.y, H1.x, H1.y);
    *(uint4*)&ql[u] = make_uint4(L0.x, L0.y, L1.x, L1.y);
}

// K1: 768 blocks; r = bid%3. r<2: MFMA block (4 waves x 4 m-tiles, 64 q);
// r==2: out-sum streamer (32 m). MFMA: wave-private LDS (hi/lo packed uint4
// slots, pc ^= row&7 swizzle), zero barriers, FIFO-monotone loads (counted
// vmcnt only). Weighted in f-sum from staging regs: 8 FMAs + 1 xor-8 shuffle.
__global__ __launch_bounds__(256, 3) void k_att(
    const short8v* __restrict__ qhg, const short8v* __restrict__ qlg,
    const float* __restrict__ in_mem, const float* __restrict__ out_mem,
    const float* __restrict__ ctx_mask, const float* __restrict__ query_mask,
    float* __restrict__ att_qm, float* __restrict__ in_mem_base,
    float* __restrict__ out_mem_sum)
{
    __shared__ __align__(16) uint4 SB[4][512];   // 32 KB: wave-private 64 rows x 8 slots

    const int bid = blockIdx.x;
    const int u = bid / 3, r = bid - u * 3;
    const int t = threadIdx.x;

    if (r == 2) {
        // ---------------- out-sum streamer: 32 m ----------------
        const int b = u >> 4;
        const int m = (u & 15) * 32 + (t >> 3), c = t & 7;
        const float4* src = (const float4*)out_mem + (size_t)((b * M_ + m) * F_) * 128;
        float4* dst = (float4*)out_mem_sum + (size_t)(b * M_ + m) * 128;
        #pragma unroll
        for (int j = 0; j < 16; ++j) {
            int col = c + j * 8;
            float4 sv = make_float4(0, 0, 0, 0);
            #pragma unroll
            for (int f = 0; f < 16; ++f) {
                float4 v = src[f * 128 + col];
                sv.x += v.x; sv.y += v.y; sv.z += v.z; sv.w += v.w;
            }
            dst[col] = sv;
        }
        return;
    }

    // ---------------- MFMA path ----------------
    const int k   = u * 2 + r;            // 0..511
    const int b   = k >> 5;
    const int m0  = (k & 31) * 16;
    const int w   = t >> 6, lane = t & 63;
    const int mw0 = m0 + w * 4;           // wave's 4 m
    // staging map
    const int mm = lane >> 4;             // my m (0..3)
    const int h  = (lane >> 3) & 1;       // f-half
    const int c  = lane & 7;              // float4 col
    // fragment map
    const int lr = lane & 15, lg = lane >> 4;

    uint4* Wb = SB[w];

    // softmax-over-f weights for my m, f = h*8 + i
    float wj[8];
    {
        const float* cm = ctx_mask + (size_t)(b * M_ + mw0 + mm) * F_;
        float wv[16]; float mx = -INF_F;
        #pragma unroll
        for (int f = 0; f < 16; ++f) {
            float cv = cm[f];
            float v = cv - (1.0f - cv) * INF_F;
            wv[f] = v; mx = fmaxf(mx, v);
        }
        float s = 0.f;
        #pragma unroll
        for (int f = 0; f < 16; ++f) { wv[f] = __expf(wv[f] - mx); s += wv[f]; }
        float inv = 1.0f / s;
        #pragma unroll
        for (int i = 0; i < 8; ++i) wj[i] = wv[h * 8 + i] * inv;
    }

    const float4* in4 = (const float4*)in_mem;
    const size_t gb = (size_t)((b * M_ + mw0 + mm) * F_ + h * 8) * 128 + c;  // + i*128 + kc*8
    const size_t ob = (size_t)(b * M_ + mw0 + mm) * 128 + c;                 // + kc*8
    const int qb0 = b * 4096 + lg * 64 + lr;                                 // + kc*256 + tq*16

    f32x4 acc[4][4];
    #pragma unroll
    for (int i = 0; i < 4; ++i)
        #pragma unroll
        for (int j = 0; j < 4; ++j) acc[i][j] = (f32x4){0, 0, 0, 0};

    float4 si[8];
    short8v qf[8];

    // prologue (FIFO: si then qf)
    #pragma unroll
    for (int i = 0; i < 8; ++i) si[i] = in4[gb + (size_t)i * 128];
    #pragma unroll
    for (int tq = 0; tq < 4; ++tq) { qf[2*tq] = qhg[qb0 + tq*16]; qf[2*tq+1] = qlg[qb0 + tq*16]; }

    #pragma unroll
    for (int kc = 0; kc < 16; ++kc) {
        // a: consume si -> LDS (packed hi/lo uint4) + weighted partial
        float4 fs = make_float4(0, 0, 0, 0);
        #pragma unroll
        for (int i = 0; i < 8; ++i) {
            float4 v = si[i];
            uint2 H, L; split4(v, H, L);
            int row = mm * 16 + h * 8 + i;
            Wb[row * 8 + (c ^ (row & 7))] = make_uint4(H.x, H.y, L.x, L.y);
            fs.x += wj[i]*v.x; fs.y += wj[i]*v.y; fs.z += wj[i]*v.z; fs.w += wj[i]*v.w;
        }
        // b: fold f-halves + store (writers h==0)
        fs.x += __shfl_xor(fs.x, 8, 64); fs.y += __shfl_xor(fs.y, 8, 64);
        fs.z += __shfl_xor(fs.z, 8, 64); fs.w += __shfl_xor(fs.w, 8, 64);
        if (h == 0) ((float4*)in_mem_base)[ob + kc * 8] = fs;
        // c: issue next chunk's data loads (stay in flight across MFMA)
        if (kc < 15) {
            #pragma unroll
            for (int i = 0; i < 8; ++i) si[i] = in4[gb + (size_t)i * 128 + (kc + 1) * 8];
        }
        // d: MFMA from wave-private LDS (DS wave-ordered; no barrier)
        __builtin_amdgcn_s_setprio(1);
        #pragma unroll
        for (int tm = 0; tm < 4; ++tm) {
            int row = tm * 16 + lr;
            uint4 s0 = Wb[row * 8 + ((lg * 2)     ^ (lr & 7))];
            uint4 s1 = Wb[row * 8 + ((lg * 2 + 1) ^ (lr & 7))];
            short8v bh = mk8(make_uint2(s0.x, s0.y), make_uint2(s1.x, s1.y));
            short8v bl = mk8(make_uint2(s0.z, s0.w), make_uint2(s1.z, s1.w));
            #pragma unroll
            for (int tq = 0; tq < 4; ++tq) {
                short8v ah = qf[2*tq], al = qf[2*tq+1];
                acc[tm][tq] = __builtin_amdgcn_mfma_f32_16x16x32_bf16(ah, bh, acc[tm][tq], 0, 0, 0);
                acc[tm][tq] = __builtin_amdgcn_mfma_f32_16x16x32_bf16(ah, bl, acc[tm][tq], 0, 0, 0);
                acc[tm][tq] = __builtin_amdgcn_mfma_f32_16x16x32_bf16(al, bh, acc[tm][tq], 0, 0, 0);
            }
        }
        __builtin_amdgcn_s_setprio(0);
        // e: issue next chunk's q-fragments (L2-hot)
        if (kc < 15) {
            int qb = qb0 + (kc + 1) * 256;
            #pragma unroll
            for (int tq = 0; tq < 4; ++tq) { qf[2*tq] = qhg[qb + tq*16]; qf[2*tq+1] = qlg[qb + tq*16]; }
        }
    }

    // masks + max over f (16-lane groups) -> att_qm; wave owns 4 m
    #pragma unroll
    for (int tm = 0; tm < 4; ++tm) {
        int m = mw0 + tm;
        float cmv = ctx_mask[(size_t)(b * M_ + m) * F_ + lr];
        #pragma unroll
        for (int tq = 0; tq < 4; ++tq) {
            #pragma unroll
            for (int rg = 0; rg < 4; ++rg) {
                int q = tq * 16 + lg * 4 + rg;
                float qmv = query_mask[b * Q_ + q];
                float v = acc[tm][tq][rg];
                v = cmv * v - (1.0f - cmv) * INF_F;
                v = qmv * v - (1.0f - qmv) * INF_F;
                #pragma unroll
                for (int sh = 1; sh < 16; sh <<= 1) v = fmaxf(v, __shfl_xor(v, sh, 64));
                if (lr == 0)
                    att_qm[(size_t)(b * Q_ + q) * M_ + m] = v;
            }
        }
    }
}

// K2: softmax over M (in-block) + new_query = query + probs @ out_mem_sum; 8 q/block
__global__ __launch_bounds__(128) void k_new_query(
    const float* __restrict__ att, const float* __restrict__ query,
    const float* __restrict__ out_sum, float* __restrict__ new_q)
{
    __shared__ float P[8][512];
    int bid = blockIdx.x;
    int b = bid & 15, qc = bid >> 4;
    int t = threadIdx.x;
    {
        int qi = t >> 4, l16 = t & 15;
        const float* row = att + (size_t)(b * Q_ + qc * 8 + qi) * M_;
        float vals[32]; float mx = -INF_F;
        #pragma unroll
        for (int i = 0; i < 32; ++i) { vals[i] = row[l16 + i * 16]; mx = fmaxf(mx, vals[i]); }
        #pragma unroll
        for (int s = 1; s < 16; s <<= 1) mx = fmaxf(mx, __shfl_xor(mx, s, 64));
        float sm = 0.f;
        #pragma unroll
        for (int i = 0; i < 32; ++i) { vals[i] = __expf(vals[i] - mx); sm += vals[i]; }
        #pragma unroll
        for (int s = 1; s < 16; s <<= 1) sm += __shfl_xor(sm, s, 64);
        float inv = 1.0f / sm;
        #pragma unroll
        for (int i = 0; i < 32; ++i) P[qi][l16 + i * 16] = vals[i] * inv;
    }
    __syncthreads();
    int c = t;
    const float4* o4 = (const float4*)out_sum + (size_t)b * M_ * 128 + c;
    const float4* q4 = (const float4*)query + (size_t)(b * Q_ + qc * 8) * 128 + c;
    float4 acc[8];
    #pragma unroll
    for (int qi = 0; qi < 8; ++qi) acc[qi] = q4[(size_t)qi * 128];
    for (int mm = 0; mm < M_; mm += 4) {
        float4 o0 = o4[(size_t)(mm + 0) * 128];
        float4 o1 = o4[(size_t)(mm + 1) * 128];
        float4 o2 = o4[(size_t)(mm + 2) * 128];
        float4 o3 = o4[(size_t)(mm + 3) * 128];
        #pragma unroll
        for (int qi = 0; qi < 8; ++qi) {
            float4 p = *(const float4*)&P[qi][mm];
            acc[qi].x += p.x * o0.x + p.y * o1.x + p.z * o2.x + p.w * o3.x;
            acc[qi].y += p.x * o0.y + p.y * o1.y + p.z * o2.y + p.w * o3.y;
            acc[qi].z += p.x * o0.z + p.y * o1.z + p.z * o2.z + p.w * o3.z;
            acc[qi].w += p.x * o0.w + p.y * o1.w + p.z * o2.w + p.w * o3.w;
        }
    }
    float4* n4 = (float4*)new_q + (size_t)(b * Q_ + qc * 8) * 128 + c;
    #pragma unroll
    for (int qi = 0; qi < 8; ++qi) n4[(size_t)qi * 128] = acc[qi];
}

// K3: softmax over Q (in-block) + in_mem += p2 @ new_query; 8 m/block
__global__ __launch_bounds__(128) void k_in_mem(
    const float* __restrict__ att, const float* __restrict__ new_q,
    float* __restrict__ in_mem_io)
{
    __shared__ float P[8][64];
    int bid = blockIdx.x;
    int b = bid & 15, mc = bid >> 4;
    int m0 = mc * 8;
    int t = threadIdx.x;
    {
        int mi = t >> 4, l16 = t & 15;
        float v[4]; float mx = -INF_F;
        #pragma unroll
        for (int i = 0; i < 4; ++i) {
            v[i] = att[(size_t)(b * Q_ + l16 + i * 16) * M_ + m0 + mi];
            mx = fmaxf(mx, v[i]);
        }
        #pragma unroll
        for (int s = 1; s < 16; s <<= 1) mx = fmaxf(mx, __shfl_xor(mx, s, 64));
        float sm = 0.f;
        #pragma unroll
        for (int i = 0; i < 4; ++i) { v[i] = __expf(v[i] - mx); sm += v[i]; }
        #pragma unroll
        for (int s = 1; s < 16; s <<= 1) sm += __shfl_xor(sm, s, 64);
        float inv = 1.0f / sm;
        #pragma unroll
        for (int i = 0; i < 4; ++i) P[mi][l16 + i * 16] = v[i] * inv;
    }
    __syncthreads();
    int c = t;
    float4* io = (float4*)in_mem_io + (size_t)(b * M_ + m0) * 128 + c;
    const float4* n4 = (const float4*)new_q + (size_t)b * Q_ * 128 + c;
    float4 acc[8];
    #pragma unroll
    for (int mi = 0; mi < 8; ++mi) acc[mi] = io[(size_t)mi * 128];
    for (int q = 0; q < Q_; q += 4) {
        float4 n0 = n4[(size_t)(q + 0) * 128];
        float4 n1 = n4[(size_t)(q + 1) * 128];
        float4 n2 = n4[(size_t)(q + 2) * 128];
        float4 n3 = n4[(size_t)(q + 3) * 128];
        #pragma unroll
        for (int mi = 0; mi < 8; ++mi) {
            float4 p = *(const float4*)&P[mi][q];
            acc[mi].x += p.x * n0.x + p.y * n1.x + p.z * n2.x + p.w * n3.x;
            acc[mi].y += p.x * n0.y + p.y * n1.y + p.z * n2.y + p.w * n3.y;
            acc[mi].z += p.x * n0.z + p.y * n1.z + p.z * n2.z + p.w * n3.z;
            acc[mi].w += p.x * n0.w + p.y * n1.w + p.z * n2.w + p.w * n3.w;
        }
    }
    #pragma unroll
    for (int mi = 0; mi < 8; ++mi) io[(size_t)mi * 128] = acc[mi];
}

extern "C" void kernel_launch(void* const* d_in, const int* in_sizes, int n_in,
                              void* d_out, int out_size, void* d_ws, size_t ws_size,
                              hipStream_t stream)
{
    const float* query      = (const float*)d_in[0];
    const float* in_mem     = (const float*)d_in[1];
    const float* out_mem    = (const float*)d_in[2];
    const float* ctx_mask   = (const float*)d_in[3];
    const float* query_mask = (const float*)d_in[4];

    float* out = (float*)d_out;
    float* new_q      = out;                             // B*Q*D
    float* in_mem_out = out + (size_t)B_*Q_*D_;          // B*M*D
    float* out_mem_o  = in_mem_out + (size_t)B_*M_*D_;   // B*M*D

    float* ws       = (float*)d_ws;
    float* att_qm   = ws;                                // B*Q*M floats (2 MB)
    short8v* qh     = (short8v*)(ws + (size_t)B_*Q_*M_); // 65536 units (1 MB)
    short8v* ql     = qh + 65536;                        // 1 MB

    hipLaunchKernelGGL(k_q_split, dim3(256), dim3(256), 0, stream, query, qh, ql);
    hipLaunchKernelGGL(k_att, dim3(768), dim3(256), 0, stream,
                       qh, ql, in_mem, out_mem, ctx_mask, query_mask,
                       att_qm, in_mem_out, out_mem_o);
    hipLaunchKernelGGL(k_new_query, dim3(8 * B_), dim3(128), 0, stream,
                       att_qm, query, out_mem_o, new_q);
    hipLaunchKernelGGL(k_in_mem, dim3(64 * B_), dim3(128), 0, stream,
                       att_qm, new_q, in_mem_out);
}